// Round 4
// baseline (9089.651 us; speedup 1.0000x reference)
//
#include <hip/hip_runtime.h>
#include <math.h>

#define BD 256
#define NB 16
#define DIM 1024
#define SMAX 288
#define NSTEPS 32
#define NPROPS 512
#define NBLK 512
#define NTOK (16 * 256 * 1024)

// ---------- coherent (L2-bypassing, relaxed) access helpers ----------
__device__ __forceinline__ double cload(const double* p) {
    return __hip_atomic_load(p, __ATOMIC_RELAXED, __HIP_MEMORY_SCOPE_AGENT);
}
__device__ __forceinline__ void cstore(double* p, double v) {
    __hip_atomic_store(p, v, __ATOMIC_RELAXED, __HIP_MEMORY_SCOPE_AGENT);
}

// ---------- reductions ----------
__device__ __forceinline__ double wred_sum(double v) {
#pragma unroll
    for (int o = 32; o > 0; o >>= 1) v += __shfl_down(v, o, 64);
    return v;
}
__device__ __forceinline__ double wred_max(double v) {
#pragma unroll
    for (int o = 32; o > 0; o >>= 1) { double w = __shfl_down(v, o, 64); if (w > v) v = w; }
    return v;
}
__device__ __forceinline__ double block_sum(double v, double* sc) {
    v = wred_sum(v);
    int tid = threadIdx.x;
    if ((tid & 63) == 0) sc[tid >> 6] = v;
    __syncthreads();
    double r = sc[0] + sc[1] + sc[2] + sc[3];
    __syncthreads();
    return r;
}
__device__ __forceinline__ double block_max(double v, double* sc) {
    v = wred_max(v);
    int tid = threadIdx.x;
    if ((tid & 63) == 0) sc[tid >> 6] = v;
    __syncthreads();
    double r = fmax(fmax(sc[0], sc[1]), fmax(sc[2], sc[3]));
    __syncthreads();
    return r;
}

// ---------- fence-free grid barrier (round-2 arrival + 64-line release) ----------
// Arrival: 16 leaf counters x 32 arrivals + root counter (proven in round 2).
// Release: the completing thread broadcasts the release value to 64 replicated
// cachelines; each block polls only line (bid & 63) -> 8 pollers/line instead
// of 511 pollers on one line (the measured ~16us stagger in round 2).
// Monotone values, relaxed atomics only, no cache maintenance. Data
// visibility: __syncthreads() drains vmcnt(0) per wave before arrival, so all
// coherent stores are at the coherence point before the arrival is visible.
// bar layout (uints): leaves at [g*32] g=0..15, root at [512],
// release lines at [1024 + i*32] i=0..63.
__device__ __forceinline__ void gridbar(unsigned* bar, int bid) {
    __syncthreads();
    if (threadIdx.x == 0) {
        unsigned* leaf = bar + ((bid & 15) << 5);
        unsigned a = __hip_atomic_fetch_add(leaf, 1u, __ATOMIC_RELAXED, __HIP_MEMORY_SCOPE_AGENT);
        if ((a & 31u) == 31u) {  // 32nd arrival on this leaf for this phase
            unsigned r = __hip_atomic_fetch_add(bar + 512, 1u, __ATOMIC_RELAXED, __HIP_MEMORY_SCOPE_AGENT);
            if ((r & 15u) == 15u) {  // 16th leaf completion -> release phase
                unsigned relv = (r >> 4) + 1u;
#pragma unroll
                for (int i = 0; i < 64; ++i)
                    __hip_atomic_store(bar + 1024 + i * 32, relv, __ATOMIC_RELAXED, __HIP_MEMORY_SCOPE_AGENT);
            }
        }
        unsigned target = (a >> 5) + 1u;
        const unsigned* myline = bar + 1024 + ((bid & 63) << 5);
        while ((int)(__hip_atomic_load(myline, __ATOMIC_RELAXED, __HIP_MEMORY_SCOPE_AGENT) - target) < 0)
            __builtin_amdgcn_s_sleep(2);
    }
    __syncthreads();
}

// ---- canonicalize tokens: handles harness passing int32 OR raw int64 ----
__global__ __launch_bounds__(256) void k_tok_convert(const int* __restrict__ tok32,
                                                     signed char* __restrict__ tokc) {
    __shared__ int flag;
    int tid = threadIdx.x;
    if (tid == 0) {
        int nz = 0;
        for (int i = 1; i < 512; i += 2) nz |= tok32[i];
        flag = nz;
    }
    __syncthreads();
    bool is64 = (flag == 0);
#pragma unroll
    for (int it = 0; it < 4; ++it) {
        size_t idx = (size_t)blockIdx.x * 1024 + it * BD + tid;
        int v = is64 ? tok32[2 * idx] : tok32[idx];
        tokc[idx] = (signed char)v;
    }
}

// ---- prefix: per-token LN stats ----
__global__ __launch_bounds__(256) void k_prefix_stats(const signed char* __restrict__ tokc,
                                                      double* __restrict__ mu, double* __restrict__ rs) {
    __shared__ double sc[4];
    int T = blockIdx.x, tid = threadIdx.x;
    const signed char* row = tokc + (size_t)T * DIM;
    double s = 0;
    for (int i = tid; i < DIM; i += BD) s += (double)row[i];
    s = block_sum(s, sc);
    double m = s * (1.0 / 1024.0);
    double ss = 0;
    for (int i = tid; i < DIM; i += BD) { double d = (double)row[i] - m; ss += d * d; }
    ss = block_sum(ss, sc);
    if (tid == 0) { mu[T] = m; rs[T] = 1.0 / sqrt(ss * (1.0 / 1024.0) + 1e-5); }
}

__global__ __launch_bounds__(256) void k_init_xl(const signed char* __restrict__ tokc,
                                                 double* __restrict__ xl, unsigned* __restrict__ bar) {
    int b = blockIdx.x, tid = threadIdx.x;
    if (b == 0) for (int i = tid; i < 4096; i += BD) bar[i] = 0u;
    for (int i = tid; i < DIM; i += BD)
        xl[b * DIM + i] = (double)tokc[((size_t)b * 256 + 255) * DIM + i];
}

// ---- prefix K,V GEMM: [4096 tokens x 1024] @ Wqkv[:,1024:3072], fp64 ----
__global__ __launch_bounds__(256) void k_prefix(const signed char* __restrict__ tokc,
        const double* __restrict__ mu, const double* __restrict__ rs,
        const float* __restrict__ Wqkv, const float* __restrict__ bqkv,
        const float* __restrict__ g1, const float* __restrict__ b1,
        double* __restrict__ Kc, double* __restrict__ Vc) {
    __shared__ double Hs[64 * 17];
    __shared__ float  Ws[64 * 64];
    int tid = threadIdx.x;
    int tx = tid & 63, ty = tid >> 6;
    int j0 = blockIdx.x * 64;
    int T0 = blockIdx.y * 16;
    double acc[4] = {0, 0, 0, 0};
    for (int kc = 0; kc < DIM; kc += 64) {
#pragma unroll
        for (int it = 0; it < 4; ++it) {
            int idx = tid + it * BD;
            int t = idx & 15, k = idx >> 4;
            int T = T0 + t;
            double x = (double)tokc[(size_t)T * DIM + kc + k];
            Hs[k * 17 + t] = (x - mu[T]) * rs[T] * (double)g1[kc + k] + (double)b1[kc + k];
        }
#pragma unroll
        for (int it = 0; it < 16; ++it) {
            int idx = tid + it * BD;
            int k = idx >> 6, j = idx & 63;
            Ws[k * 64 + j] = Wqkv[(size_t)(kc + k) * 3072 + 1024 + j0 + j];
        }
        __syncthreads();
#pragma unroll 8
        for (int k = 0; k < 64; ++k) {
            double w = (double)Ws[k * 64 + tx];
            acc[0] += Hs[k * 17 + ty * 4 + 0] * w;
            acc[1] += Hs[k * 17 + ty * 4 + 1] * w;
            acc[2] += Hs[k * 17 + ty * 4 + 2] * w;
            acc[3] += Hs[k * 17 + ty * 4 + 3] * w;
        }
        __syncthreads();
    }
    int colg = j0 + tx;
    double bias = (double)bqkv[1024 + colg];
    bool isK = (colg < 1024);
#pragma unroll
    for (int a = 0; a < 4; ++a) {
        int T = T0 + ty * 4 + a;
        int b = T >> 8, pos = T & 255;
        double v = acc[a] + bias;
        if (isK) Kc[((size_t)b * SMAX + pos) * DIM + colg] = v;
        else     Vc[((size_t)b * SMAX + pos) * DIM + colg - 1024] = v;
    }
}

// ---- LN of last token (t=0 only) ----
__global__ __launch_bounds__(256) void k_ln1(const double* __restrict__ xl, const float* __restrict__ g,
                                             const float* __restrict__ bb, double* __restrict__ h1) {
    __shared__ double xs[DIM];
    __shared__ double sc[4];
    int b = blockIdx.x, tid = threadIdx.x;
    for (int i = tid; i < DIM; i += BD) xs[i] = xl[b * DIM + i];
    __syncthreads();
    double s = 0;
    for (int i = tid; i < DIM; i += BD) s += xs[i];
    s = block_sum(s, sc);
    double m = s * (1.0 / 1024.0);
    double ss = 0;
    for (int i = tid; i < DIM; i += BD) { double d = xs[i] - m; ss += d * d; }
    ss = block_sum(ss, sc);
    double r = 1.0 / sqrt(ss * (1.0 / 1024.0) + 1e-5);
    for (int i = tid; i < DIM; i += BD)
        h1[b * DIM + i] = (xs[i] - m) * r * (double)g[i] + (double)bb[i];
}

// ---------- GEMV tile helpers (16 rows x 64 cols, K-slice klen) ----------
__device__ __forceinline__ void gemv_std(const double* __restrict__ A, int lda,
        const float* __restrict__ W, int ldw, double* __restrict__ P, int ncols,
        int j0, int k0, int klen, int ks, double* As, float* Ws) {
    int tid = threadIdx.x, tx = tid & 63, ty = tid >> 6;
    double a0 = 0, a1 = 0, a2 = 0, a3 = 0;
    for (int kc = 0; kc < klen; kc += 64) {
#pragma unroll
        for (int it = 0; it < 4; ++it) {
            int idx = tid + it * BD;
            int b = idx >> 6, k = idx & 63;
            As[b * 64 + k] = cload(&A[(size_t)b * lda + k0 + kc + k]);
        }
#pragma unroll
        for (int it = 0; it < 16; ++it) {
            int idx = tid + it * BD;
            int k = idx >> 6, j = idx & 63;
            Ws[k * 64 + j] = W[(size_t)(k0 + kc + k) * ldw + j0 + j];
        }
        __syncthreads();
#pragma unroll 8
        for (int k = 0; k < 64; ++k) {
            double w = (double)Ws[k * 64 + tx];
            a0 += As[(ty * 4 + 0) * 64 + k] * w;
            a1 += As[(ty * 4 + 1) * 64 + k] * w;
            a2 += As[(ty * 4 + 2) * 64 + k] * w;
            a3 += As[(ty * 4 + 3) * 64 + k] * w;
        }
        __syncthreads();
    }
    size_t base = (size_t)(ks * 16 + ty * 4) * ncols + j0 + tx;
    cstore(&P[base], a0);
    cstore(&P[base + (size_t)ncols], a1);
    cstore(&P[base + (size_t)2 * ncols], a2);
    cstore(&P[base + (size_t)3 * ncols], a3);
}

// A is 8 partial buffers AOp[s][16][DIM], summed during staging
__device__ __forceinline__ void gemv_sum8(const double* __restrict__ Ap,
        const float* __restrict__ W, int ldw, double* __restrict__ P, int ncols,
        int j0, int k0, int klen, int ks, double* As, float* Ws) {
    int tid = threadIdx.x, tx = tid & 63, ty = tid >> 6;
    double a0 = 0, a1 = 0, a2 = 0, a3 = 0;
    for (int kc = 0; kc < klen; kc += 64) {
#pragma unroll
        for (int it = 0; it < 4; ++it) {
            int idx = tid + it * BD;
            int b = idx >> 6, k = idx & 63;
            const double* col = Ap + (size_t)b * DIM + k0 + kc + k;
            double s = 0;
#pragma unroll
            for (int sct = 0; sct < 8; ++sct) s += cload(&col[(size_t)sct * 16 * DIM]);
            As[b * 64 + k] = s;
        }
#pragma unroll
        for (int it = 0; it < 16; ++it) {
            int idx = tid + it * BD;
            int k = idx >> 6, j = idx & 63;
            Ws[k * 64 + j] = W[(size_t)(k0 + kc + k) * ldw + j0 + j];
        }
        __syncthreads();
#pragma unroll 8
        for (int k = 0; k < 64; ++k) {
            double w = (double)Ws[k * 64 + tx];
            a0 += As[(ty * 4 + 0) * 64 + k] * w;
            a1 += As[(ty * 4 + 1) * 64 + k] * w;
            a2 += As[(ty * 4 + 2) * 64 + k] * w;
            a3 += As[(ty * 4 + 3) * 64 + k] * w;
        }
        __syncthreads();
    }
    size_t base = (size_t)(ks * 16 + ty * 4) * ncols + j0 + tx;
    cstore(&P[base], a0);
    cstore(&P[base + (size_t)ncols], a1);
    cstore(&P[base + (size_t)2 * ncols], a2);
    cstore(&P[base + (size_t)3 * ncols], a3);
}

// transposed weight (W_score is [out, K])
__device__ __forceinline__ void gemv_wt(const double* __restrict__ A,
        const float* __restrict__ Wt, double* __restrict__ P, int ncols,
        int j0, int k0, int klen, int ks, double* As, float* Ws) {
    int tid = threadIdx.x, tx = tid & 63, ty = tid >> 6;
    double a0 = 0, a1 = 0, a2 = 0, a3 = 0;
    for (int kc = 0; kc < klen; kc += 64) {
#pragma unroll
        for (int it = 0; it < 4; ++it) {
            int idx = tid + it * BD;
            int b = idx >> 6, k = idx & 63;
            As[b * 64 + k] = cload(&A[(size_t)b * DIM + k0 + kc + k]);
        }
#pragma unroll
        for (int it = 0; it < 16; ++it) {
            int idx = tid + it * BD;
            int j = idx >> 6, k = idx & 63;
            Ws[k * 65 + j] = Wt[(size_t)(j0 + j) * DIM + k0 + kc + k];
        }
        __syncthreads();
#pragma unroll 8
        for (int k = 0; k < 64; ++k) {
            double w = (double)Ws[k * 65 + tx];
            a0 += As[(ty * 4 + 0) * 64 + k] * w;
            a1 += As[(ty * 4 + 1) * 64 + k] * w;
            a2 += As[(ty * 4 + 2) * 64 + k] * w;
            a3 += As[(ty * 4 + 3) * 64 + k] * w;
        }
        __syncthreads();
    }
    size_t base = (size_t)(ks * 16 + ty * 4) * ncols + j0 + tx;
    cstore(&P[base], a0);
    cstore(&P[base + (size_t)ncols], a1);
    cstore(&P[base + (size_t)2 * ncols], a2);
    cstore(&P[base + (size_t)3 * ncols], a3);
}

// ---------- the persistent step-loop kernel ----------
__global__ __launch_bounds__(256, 2) void k_steps(
    const float* __restrict__ Wqkv, const float* __restrict__ bqkv,
    const float* __restrict__ Wap,  const float* __restrict__ bap,
    const float* __restrict__ g1,   const float* __restrict__ b1,
    const float* __restrict__ g2,   const float* __restrict__ b2,
    const float* __restrict__ Wfc,  const float* __restrict__ bfc,
    const float* __restrict__ Wmp,  const float* __restrict__ bmp,
    const float* __restrict__ gf,   const float* __restrict__ bf,
    const float* __restrict__ Wsc,
    double* __restrict__ Kc, double* __restrict__ Vc,
    double* __restrict__ xl, double* __restrict__ h1,
    double* __restrict__ q,  double* __restrict__ sco,
    double* __restrict__ AOp, double* __restrict__ x2,
    double* __restrict__ h2, double* __restrict__ m_,
    double* __restrict__ hf,
    double* __restrict__ P1, double* __restrict__ P2, double* __restrict__ P3,
    double* __restrict__ P4, double* __restrict__ P5,
    float* __restrict__ out, unsigned* __restrict__ bar)
{
    // overlaid LDS: region A (8KB: As / qs / ps / xs), region B (16.25KB: Ws), red (32B)
    __shared__ __align__(16) char smem[24864];
    double* As  = (double*)smem;
    float*  Ws  = (float*)(smem + 8192);
    double* red = (double*)(smem + 24832);
    int bid = blockIdx.x, tid = threadIdx.x;

    for (int t = 0; t < NSTEPS; ++t) {
        int S = 256 + t, pos = 255 + t;

        // -- 1: QKV GEMV (h1 @ Wqkv) -> P1 partials. 48 col-tiles x splitK8
        if (bid < 384)
            gemv_std(h1, DIM, Wqkv, 3072, P1, 3072,
                     (bid % 48) * 64, (bid / 48) * 128, 128, bid / 48, As, Ws);
        gridbar(bar, bid);

        // -- 2: combine partials -> q, append K[pos], V[pos]
        if (bid < 48) {
            int col = bid * 64 + (tid & 63);
            for (int bb = (tid >> 6); bb < 16; bb += 4) {
                double s = (double)bqkv[col];
#pragma unroll
                for (int ks = 0; ks < 8; ++ks) s += cload(&P1[((size_t)(ks * 16 + bb)) * 3072 + col]);
                if (col < 1024)      cstore(&q[bb * DIM + col], s);
                else if (col < 2048) cstore(&Kc[((size_t)bb * SMAX + pos) * DIM + (col - 1024)], s);
                else                 cstore(&Vc[((size_t)bb * SMAX + pos) * DIM + (col - 2048)], s);
            }
        }
        gridbar(bar, bid);

        // -- 3: attention scores. 384 blocks: b x 24 chunks x 12 pos
        if (bid < 384) {
            int b = bid / 24, c = bid % 24;
            double* qs = As;
            for (int i = tid; i < DIM; i += BD) qs[i] = cload(&q[b * DIM + i]);
            __syncthreads();
            int w = tid >> 6, lane = tid & 63;
#pragma unroll
            for (int r = 0; r < 3; ++r) {
                int p = c * 12 + w * 3 + r;
                if (p < S) {
                    const double* kp = Kc + ((size_t)b * SMAX + p) * DIM;
                    double acc = 0;
                    if (p == pos) {
#pragma unroll
                        for (int ii = 0; ii < 16; ++ii) acc += qs[lane + 64 * ii] * cload(&kp[lane + 64 * ii]);
                    } else {
#pragma unroll
                        for (int ii = 0; ii < 16; ++ii) acc += qs[lane + 64 * ii] * kp[lane + 64 * ii];
                    }
                    acc = wred_sum(acc);
                    if (lane == 0) cstore(&sco[b * SMAX + p], acc * 0.03125);  // /sqrt(1024)
                }
            }
        }
        gridbar(bar, bid);

        // -- 4: softmax (redundant per block) + partial PV. 512 blocks: b x 4 dchunk x 8 schunk
        {
            int b = bid >> 5, sub = bid & 31;
            int dch = sub & 3, sch = sub >> 2;
            double* ps = As;
            double lm = -1e300;
            for (int i = tid; i < S; i += BD) { double v = cload(&sco[b * SMAX + i]); ps[i] = v; lm = fmax(lm, v); }
            double mx = block_max(lm, red);
            double le = 0;
            for (int i = tid; i < S; i += BD) { double e = exp(ps[i] - mx); ps[i] = e; le += e; }
            double den = block_sum(le, red);
            int d = dch * 256 + tid;
            int p0 = sch * 36, p1 = p0 + 36; if (p1 > S) p1 = S;
            bool fresh = (p1 == S);            // range containing pos == S-1
            int pe = fresh ? p1 - 1 : p1;
            const double* Vb = Vc + (size_t)b * SMAX * DIM + d;
            double a0 = 0, a1 = 0, a2 = 0, a3 = 0;
            int p = p0;
            for (; p + 4 <= pe; p += 4) {
                a0 += ps[p + 0] * Vb[(size_t)(p + 0) * DIM];
                a1 += ps[p + 1] * Vb[(size_t)(p + 1) * DIM];
                a2 += ps[p + 2] * Vb[(size_t)(p + 2) * DIM];
                a3 += ps[p + 3] * Vb[(size_t)(p + 3) * DIM];
            }
            for (; p < pe; ++p) a0 += ps[p] * Vb[(size_t)p * DIM];
            if (fresh) a0 += ps[pos] * cload(&Vb[(size_t)pos * DIM]);
            cstore(&AOp[((size_t)(sch * 16 + b)) * DIM + d], ((a0 + a1) + (a2 + a3)) / den);
        }
        gridbar(bar, bid);

        // -- 5: attn-proj GEMV (sum 8 AOp partials during staging). 16 tiles x splitK8
        if (bid < 128)
            gemv_sum8(AOp, Wap, DIM, P2, DIM,
                      (bid % 16) * 64, (bid / 16) * 128, 128, bid / 16, As, Ws);
        gridbar(bar, bid);

        // -- 6: x2 = xl + aproj + bias; LN2 -> h2. 16 blocks
        if (bid < 16) {
            int b = bid;
            double* xs = As;
            for (int i = tid; i < DIM; i += BD) {
                double s = cload(&xl[b * DIM + i]) + (double)bap[i];
#pragma unroll
                for (int ks = 0; ks < 8; ++ks) s += cload(&P2[((size_t)(ks * 16 + b)) * DIM + i]);
                xs[i] = s; cstore(&x2[b * DIM + i], s);
            }
            __syncthreads();
            double s = 0;
            for (int i = tid; i < DIM; i += BD) s += xs[i];
            s = block_sum(s, red);
            double mean = s * (1.0 / 1024.0);
            double ss = 0;
            for (int i = tid; i < DIM; i += BD) { double dd = xs[i] - mean; ss += dd * dd; }
            ss = block_sum(ss, red);
            double r = 1.0 / sqrt(ss * (1.0 / 1024.0) + 1e-5);
            for (int i = tid; i < DIM; i += BD)
                cstore(&h2[b * DIM + i], (xs[i] - mean) * r * (double)g2[i] + (double)b2[i]);
        }
        gridbar(bar, bid);

        // -- 7: FC GEMV. 64 tiles x splitK8 = 512 blocks
        gemv_std(h2, DIM, Wfc, 4096, P3, 4096,
                 (bid % 64) * 64, (bid / 64) * 128, 128, bid / 64, As, Ws);
        gridbar(bar, bid);

        // -- 8: gelu -> m. 256 blocks
        if (bid < 256) {
            int b = bid >> 4, i = (bid & 15) * BD + tid;
            double u = (double)bfc[i];
#pragma unroll
            for (int ks = 0; ks < 8; ++ks) u += cload(&P3[((size_t)(ks * 16 + b)) * 4096 + i]);
            double inner = 0.7978845608028654 * (u + 0.044715 * u * u * u);
            cstore(&m_[(size_t)b * 4096 + i], 0.5 * u * (1.0 + tanh(inner)));
        }
        gridbar(bar, bid);

        // -- 9: MPROJ GEMV. 16 tiles x splitK16 (klen 256) = 256 blocks
        if (bid < 256)
            gemv_std(m_, 4096, Wmp, DIM, P4, DIM,
                     (bid % 16) * 64, (bid / 16) * 256, 256, bid / 16, As, Ws);
        gridbar(bar, bid);

        // -- 10: x3 = x2 + mproj + bias; LNf -> hf. 16 blocks
        if (bid < 16) {
            int b = bid;
            double* xs = As;
            for (int i = tid; i < DIM; i += BD) {
                double s = cload(&x2[b * DIM + i]) + (double)bmp[i];
#pragma unroll
                for (int ks = 0; ks < 16; ++ks) s += cload(&P4[((size_t)(ks * 16 + b)) * DIM + i]);
                xs[i] = s;
            }
            __syncthreads();
            double s = 0;
            for (int i = tid; i < DIM; i += BD) s += xs[i];
            s = block_sum(s, red);
            double mean = s * (1.0 / 1024.0);
            double ss = 0;
            for (int i = tid; i < DIM; i += BD) { double dd = xs[i] - mean; ss += dd * dd; }
            ss = block_sum(ss, red);
            double r = 1.0 / sqrt(ss * (1.0 / 1024.0) + 1e-5);
            for (int i = tid; i < DIM; i += BD)
                cstore(&hf[b * DIM + i], (xs[i] - mean) * r * (double)gf[i] + (double)bf[i]);
        }
        gridbar(bar, bid);

        // -- 11: classification head (W_score^T). 8 tiles x splitK8 = 64 blocks
        if (bid < 64)
            gemv_wt(hf, Wsc, P5, NPROPS,
                    (bid % 8) * 64, (bid / 8) * 128, 128, bid / 8, As, Ws);
        gridbar(bar, bid);

        // -- 12: logits + threshold -> xl, analytic LN1 -> next h1. 16 blocks
        if (bid < 16) {
            int b = bid;
            double* xs = As;
            double cnt = 0;
            for (int p = tid; p < NPROPS; p += BD) {
                double lg = 0;
#pragma unroll
                for (int ks = 0; ks < 8; ++ks) lg += cload(&P5[((size_t)(ks * 16 + b)) * NPROPS + p]);
                out[((size_t)b * NSTEPS + t) * NPROPS + p] = (float)lg;
                double bit = (lg > 0.0) ? 1.0 : 0.0;
                xs[p] = bit;
                cstore(&xl[b * DIM + p], 0.0);
                cstore(&xl[b * DIM + NPROPS + p], bit);
                cnt += bit;
            }
            double s = block_sum(cnt, red);
            double mean = s * (1.0 / 1024.0);         // row is [0]*512 + bits
            double var = mean - mean * mean;          // E[x^2]-mean^2, bits^2 = bits
            double r = 1.0 / sqrt(var + 1e-5);
            for (int i = tid; i < DIM; i += BD) {
                double x = (i < NPROPS) ? 0.0 : xs[i - NPROPS];
                cstore(&h1[b * DIM + i], (x - mean) * r * (double)g1[i] + (double)b1[i]);
            }
        }
        gridbar(bar, bid);
    }
}

extern "C" void kernel_launch(void* const* d_in, const int* in_sizes, int n_in,
                              void* d_out, int out_size, void* d_ws, size_t ws_size,
                              hipStream_t stream) {
    const int*   tok  = (const int*)d_in[0];
    const float* Wqkv = (const float*)d_in[1];
    const float* bqkv = (const float*)d_in[2];
    const float* Wap  = (const float*)d_in[3];
    const float* bap  = (const float*)d_in[4];
    const float* g1   = (const float*)d_in[5];
    const float* b1   = (const float*)d_in[6];
    const float* g2   = (const float*)d_in[7];
    const float* b2   = (const float*)d_in[8];
    const float* Wfc  = (const float*)d_in[9];
    const float* bfc  = (const float*)d_in[10];
    const float* Wmp  = (const float*)d_in[11];
    const float* bmp  = (const float*)d_in[12];
    const float* gf   = (const float*)d_in[13];
    const float* bf   = (const float*)d_in[14];
    const float* Wsc  = (const float*)d_in[15];
    float* out = (float*)d_out;

    char* w = (char*)d_ws;
    size_t off = 0;
    auto alloc = [&](size_t bytes) -> void* {
        void* p = (void*)(w + off);
        off += (bytes + 255) & ~(size_t)255;
        return p;
    };
    double*      Kc   = (double*)alloc((size_t)NB * SMAX * DIM * 8);
    double*      Vc   = (double*)alloc((size_t)NB * SMAX * DIM * 8);
    double*      mu   = (double*)alloc(4096 * 8);
    double*      rs   = (double*)alloc(4096 * 8);
    double*      xl   = (double*)alloc((size_t)NB * DIM * 8);
    double*      h1   = (double*)alloc((size_t)NB * DIM * 8);
    double*      q    = (double*)alloc((size_t)NB * DIM * 8);
    double*      sco  = (double*)alloc((size_t)NB * SMAX * 8);
    double*      AOp  = (double*)alloc((size_t)8 * NB * DIM * 8);
    double*      x2   = (double*)alloc((size_t)NB * DIM * 8);
    double*      h2   = (double*)alloc((size_t)NB * DIM * 8);
    double*      m_   = (double*)alloc((size_t)NB * 4096 * 8);
    double*      hf   = (double*)alloc((size_t)NB * DIM * 8);
    double*      P1   = (double*)alloc((size_t)8 * NB * 3072 * 8);
    double*      P2   = (double*)alloc((size_t)8 * NB * 1024 * 8);
    double*      P3   = (double*)alloc((size_t)8 * NB * 4096 * 8);
    double*      P4   = (double*)alloc((size_t)16 * NB * 1024 * 8);
    double*      P5   = (double*)alloc((size_t)8 * NB * 512 * 8);
    signed char* tokc = (signed char*)alloc((size_t)NTOK);
    unsigned*    bar  = (unsigned*)alloc(16384);
    if (off > ws_size) return;  // fail visibly (output stays poisoned)

    k_tok_convert<<<4096, BD, 0, stream>>>(tok, tokc);
    k_prefix_stats<<<4096, BD, 0, stream>>>(tokc, mu, rs);
    k_init_xl<<<NB, BD, 0, stream>>>(tokc, xl, bar);
    k_prefix<<<dim3(32, 256), BD, 0, stream>>>(tokc, mu, rs, Wqkv, bqkv, g1, b1, Kc, Vc);
    k_ln1<<<NB, BD, 0, stream>>>(xl, g1, b1, h1);

    k_steps<<<NBLK, BD, 0, stream>>>(Wqkv, bqkv, Wap, bap, g1, b1, g2, b2,
                                     Wfc, bfc, Wmp, bmp, gf, bf, Wsc,
                                     Kc, Vc, xl, h1, q, sco, AOp, x2, h2, m_, hf,
                                     P1, P2, P3, P4, P5, out, bar);
}

// Round 5
// 8272.434 us; speedup vs baseline: 1.0988x; 1.0988x over previous
//
#include <hip/hip_runtime.h>
#include <math.h>

#define BD 256
#define NB 16
#define DIM 1024
#define SMAX 288
#define NSTEPS 32
#define NPROPS 512
#define NBLK 512
#define NTOK (16 * 256 * 1024)

typedef double v2d __attribute__((ext_vector_type(2)));

// ---------- coherent access ----------
// Batched coherent loads: plain global_load with sc0 sc1 (bypass L1/L2, read at
// coherence point) issued back-to-back so they PIPELINE (atomic loads don't:
// LLVM won't reorder them -> serial latency chains, the round-2/4 bottleneck).
// Usage: issue cld2/cld1 batch, then cwait() before consuming (rule #18:
// s_waitcnt in asm needs a following sched_barrier(0)).
__device__ __forceinline__ v2d cld2(const double* p) {
    v2d r;
    asm volatile("global_load_dwordx4 %0, %1, off sc0 sc1" : "=&v"(r) : "v"(p) : "memory");
    return r;
}
__device__ __forceinline__ double cld1(const double* p) {
    double r;
    asm volatile("global_load_dwordx2 %0, %1, off sc0 sc1" : "=&v"(r) : "v"(p) : "memory");
    return r;
}
__device__ __forceinline__ void cwait() {
    asm volatile("s_waitcnt vmcnt(0)" ::: "memory");
    __builtin_amdgcn_sched_barrier(0);
}
__device__ __forceinline__ void cstore(double* p, double v) {
    __hip_atomic_store(p, v, __ATOMIC_RELAXED, __HIP_MEMORY_SCOPE_AGENT);
}

// ---------- reductions ----------
__device__ __forceinline__ double wred_sum(double v) {
#pragma unroll
    for (int o = 32; o > 0; o >>= 1) v += __shfl_down(v, o, 64);
    return v;
}
__device__ __forceinline__ double wred_max(double v) {
#pragma unroll
    for (int o = 32; o > 0; o >>= 1) { double w = __shfl_down(v, o, 64); if (w > v) v = w; }
    return v;
}
__device__ __forceinline__ double block_sum(double v, double* sc) {
    v = wred_sum(v);
    int tid = threadIdx.x;
    if ((tid & 63) == 0) sc[tid >> 6] = v;
    __syncthreads();
    double r = sc[0] + sc[1] + sc[2] + sc[3];
    __syncthreads();
    return r;
}
__device__ __forceinline__ double block_max(double v, double* sc) {
    v = wred_max(v);
    int tid = threadIdx.x;
    if ((tid & 63) == 0) sc[tid >> 6] = v;
    __syncthreads();
    double r = fmax(fmax(sc[0], sc[1]), fmax(sc[2], sc[3]));
    __syncthreads();
    return r;
}

// ---------- fence-free grid barrier (proven in rounds 2/4) ----------
__device__ __forceinline__ void gridbar(unsigned* bar, int bid) {
    __syncthreads();
    if (threadIdx.x == 0) {
        unsigned* leaf = bar + ((bid & 15) << 5);
        unsigned a = __hip_atomic_fetch_add(leaf, 1u, __ATOMIC_RELAXED, __HIP_MEMORY_SCOPE_AGENT);
        if ((a & 31u) == 31u) {
            unsigned r = __hip_atomic_fetch_add(bar + 512, 1u, __ATOMIC_RELAXED, __HIP_MEMORY_SCOPE_AGENT);
            if ((r & 15u) == 15u) {
                unsigned relv = (r >> 4) + 1u;
#pragma unroll
                for (int i = 0; i < 64; ++i)
                    __hip_atomic_store(bar + 1024 + i * 32, relv, __ATOMIC_RELAXED, __HIP_MEMORY_SCOPE_AGENT);
            }
        }
        unsigned target = (a >> 5) + 1u;
        const unsigned* myline = bar + 1024 + ((bid & 63) << 5);
        while ((int)(__hip_atomic_load(myline, __ATOMIC_RELAXED, __HIP_MEMORY_SCOPE_AGENT) - target) < 0)
            __builtin_amdgcn_s_sleep(2);
    }
    __syncthreads();
}

// ---- canonicalize tokens: handles harness passing int32 OR raw int64 ----
__global__ __launch_bounds__(256) void k_tok_convert(const int* __restrict__ tok32,
                                                     signed char* __restrict__ tokc) {
    __shared__ int flag;
    int tid = threadIdx.x;
    if (tid == 0) {
        int nz = 0;
        for (int i = 1; i < 512; i += 2) nz |= tok32[i];
        flag = nz;
    }
    __syncthreads();
    bool is64 = (flag == 0);
#pragma unroll
    for (int it = 0; it < 4; ++it) {
        size_t idx = (size_t)blockIdx.x * 1024 + it * BD + tid;
        int v = is64 ? tok32[2 * idx] : tok32[idx];
        tokc[idx] = (signed char)v;
    }
}

// ---- prefix: per-token LN stats ----
__global__ __launch_bounds__(256) void k_prefix_stats(const signed char* __restrict__ tokc,
                                                      double* __restrict__ mu, double* __restrict__ rs) {
    __shared__ double sc[4];
    int T = blockIdx.x, tid = threadIdx.x;
    const signed char* row = tokc + (size_t)T * DIM;
    double s = 0;
    for (int i = tid; i < DIM; i += BD) s += (double)row[i];
    s = block_sum(s, sc);
    double m = s * (1.0 / 1024.0);
    double ss = 0;
    for (int i = tid; i < DIM; i += BD) { double d = (double)row[i] - m; ss += d * d; }
    ss = block_sum(ss, sc);
    if (tid == 0) { mu[T] = m; rs[T] = 1.0 / sqrt(ss * (1.0 / 1024.0) + 1e-5); }
}

__global__ __launch_bounds__(256) void k_init_xl(const signed char* __restrict__ tokc,
                                                 double* __restrict__ xl, unsigned* __restrict__ bar) {
    int b = blockIdx.x, tid = threadIdx.x;
    if (b == 0) for (int i = tid; i < 4096; i += BD) bar[i] = 0u;
    for (int i = tid; i < DIM; i += BD)
        xl[b * DIM + i] = (double)tokc[((size_t)b * 256 + 255) * DIM + i];
}

// ---- prefix K,V GEMM: [4096 tokens x 1024] @ Wqkv[:,1024:3072], fp64 ----
__global__ __launch_bounds__(256) void k_prefix(const signed char* __restrict__ tokc,
        const double* __restrict__ mu, const double* __restrict__ rs,
        const float* __restrict__ Wqkv, const float* __restrict__ bqkv,
        const float* __restrict__ g1, const float* __restrict__ b1,
        double* __restrict__ Kc, double* __restrict__ Vc) {
    __shared__ double Hs[64 * 17];
    __shared__ float  Ws[64 * 64];
    int tid = threadIdx.x;
    int tx = tid & 63, ty = tid >> 6;
    int j0 = blockIdx.x * 64;
    int T0 = blockIdx.y * 16;
    double acc[4] = {0, 0, 0, 0};
    for (int kc = 0; kc < DIM; kc += 64) {
#pragma unroll
        for (int it = 0; it < 4; ++it) {
            int idx = tid + it * BD;
            int t = idx & 15, k = idx >> 4;
            int T = T0 + t;
            double x = (double)tokc[(size_t)T * DIM + kc + k];
            Hs[k * 17 + t] = (x - mu[T]) * rs[T] * (double)g1[kc + k] + (double)b1[kc + k];
        }
#pragma unroll
        for (int it = 0; it < 16; ++it) {
            int idx = tid + it * BD;
            int k = idx >> 6, j = idx & 63;
            Ws[k * 64 + j] = Wqkv[(size_t)(kc + k) * 3072 + 1024 + j0 + j];
        }
        __syncthreads();
#pragma unroll 8
        for (int k = 0; k < 64; ++k) {
            double w = (double)Ws[k * 64 + tx];
            acc[0] += Hs[k * 17 + ty * 4 + 0] * w;
            acc[1] += Hs[k * 17 + ty * 4 + 1] * w;
            acc[2] += Hs[k * 17 + ty * 4 + 2] * w;
            acc[3] += Hs[k * 17 + ty * 4 + 3] * w;
        }
        __syncthreads();
    }
    int colg = j0 + tx;
    double bias = (double)bqkv[1024 + colg];
    bool isK = (colg < 1024);
#pragma unroll
    for (int a = 0; a < 4; ++a) {
        int T = T0 + ty * 4 + a;
        int b = T >> 8, pos = T & 255;
        double v = acc[a] + bias;
        if (isK) Kc[((size_t)b * SMAX + pos) * DIM + colg] = v;
        else     Vc[((size_t)b * SMAX + pos) * DIM + colg - 1024] = v;
    }
}

// ---- LN of last token (t=0 only) ----
__global__ __launch_bounds__(256) void k_ln1(const double* __restrict__ xl, const float* __restrict__ g,
                                             const float* __restrict__ bb, double* __restrict__ h1) {
    __shared__ double xs[DIM];
    __shared__ double sc[4];
    int b = blockIdx.x, tid = threadIdx.x;
    for (int i = tid; i < DIM; i += BD) xs[i] = xl[b * DIM + i];
    __syncthreads();
    double s = 0;
    for (int i = tid; i < DIM; i += BD) s += xs[i];
    s = block_sum(s, sc);
    double m = s * (1.0 / 1024.0);
    double ss = 0;
    for (int i = tid; i < DIM; i += BD) { double d = xs[i] - m; ss += d * d; }
    ss = block_sum(ss, sc);
    double r = 1.0 / sqrt(ss * (1.0 / 1024.0) + 1e-5);
    for (int i = tid; i < DIM; i += BD)
        h1[b * DIM + i] = (xs[i] - m) * r * (double)g[i] + (double)bb[i];
}

// ---------- GEMV tile helpers (16 rows x 64 cols, K-slice klen) ----------
// As staging: thread t stages 4 contiguous doubles of row (t>>4) via 2
// pipelined coherent dwordx4 loads + one wait (was 4 serial atomic loads).
__device__ __forceinline__ void stage_as(const double* __restrict__ A, int lda,
                                         int k0, int kc, double* As, int tid) {
    int b4 = tid >> 4, kk4 = (tid & 15) * 4;
    const double* p = A + (size_t)b4 * lda + k0 + kc + kk4;
    v2d r0 = cld2(p);
    v2d r1 = cld2(p + 2);
    cwait();
    double* d = As + b4 * 64 + kk4;
    d[0] = r0.x; d[1] = r0.y; d[2] = r1.x; d[3] = r1.y;
}

__device__ __forceinline__ void gemv_std(const double* __restrict__ A, int lda,
        const float* __restrict__ W, int ldw, double* __restrict__ P, int ncols,
        int j0, int k0, int klen, int ks, double* As, float* Ws) {
    int tid = threadIdx.x, tx = tid & 63, ty = tid >> 6;
    double a0 = 0, a1 = 0, a2 = 0, a3 = 0;
    for (int kc = 0; kc < klen; kc += 64) {
        stage_as(A, lda, k0, kc, As, tid);
#pragma unroll
        for (int it = 0; it < 16; ++it) {
            int idx = tid + it * BD;
            int k = idx >> 6, j = idx & 63;
            Ws[k * 64 + j] = W[(size_t)(k0 + kc + k) * ldw + j0 + j];
        }
        __syncthreads();
#pragma unroll 8
        for (int k = 0; k < 64; ++k) {
            double w = (double)Ws[k * 64 + tx];
            a0 += As[(ty * 4 + 0) * 64 + k] * w;
            a1 += As[(ty * 4 + 1) * 64 + k] * w;
            a2 += As[(ty * 4 + 2) * 64 + k] * w;
            a3 += As[(ty * 4 + 3) * 64 + k] * w;
        }
        __syncthreads();
    }
    size_t base = (size_t)(ks * 16 + ty * 4) * ncols + j0 + tx;
    cstore(&P[base], a0);
    cstore(&P[base + (size_t)ncols], a1);
    cstore(&P[base + (size_t)2 * ncols], a2);
    cstore(&P[base + (size_t)3 * ncols], a3);
}

// A is 8 partial buffers Ap[s][16][DIM], summed during staging.
// Batched: 2 rounds of 8 pipelined dwordx4 (was 32 serial atomic loads).
__device__ __forceinline__ void gemv_sum8(const double* __restrict__ Ap,
        const float* __restrict__ W, int ldw, double* __restrict__ P, int ncols,
        int j0, int k0, int klen, int ks, double* As, float* Ws) {
    int tid = threadIdx.x, tx = tid & 63, ty = tid >> 6;
    double a0 = 0, a1 = 0, a2 = 0, a3 = 0;
    for (int kc = 0; kc < klen; kc += 64) {
        int b4 = tid >> 4, kk4 = (tid & 15) * 4;
        const double* base = Ap + (size_t)b4 * DIM + k0 + kc + kk4;
        double s0 = 0, s1 = 0, s2 = 0, s3 = 0;
#pragma unroll
        for (int half = 0; half < 2; ++half) {
            v2d ra[4], rb[4];
#pragma unroll
            for (int s4 = 0; s4 < 4; ++s4) {
                const double* pp = base + (size_t)(half * 4 + s4) * 16 * DIM;
                ra[s4] = cld2(pp);
                rb[s4] = cld2(pp + 2);
            }
            cwait();
#pragma unroll
            for (int s4 = 0; s4 < 4; ++s4) {
                s0 += ra[s4].x; s1 += ra[s4].y; s2 += rb[s4].x; s3 += rb[s4].y;
            }
        }
        double* d = As + b4 * 64 + kk4;
        d[0] = s0; d[1] = s1; d[2] = s2; d[3] = s3;
#pragma unroll
        for (int it = 0; it < 16; ++it) {
            int idx = tid + it * BD;
            int k = idx >> 6, j = idx & 63;
            Ws[k * 64 + j] = W[(size_t)(k0 + kc + k) * ldw + j0 + j];
        }
        __syncthreads();
#pragma unroll 8
        for (int k = 0; k < 64; ++k) {
            double w = (double)Ws[k * 64 + tx];
            a0 += As[(ty * 4 + 0) * 64 + k] * w;
            a1 += As[(ty * 4 + 1) * 64 + k] * w;
            a2 += As[(ty * 4 + 2) * 64 + k] * w;
            a3 += As[(ty * 4 + 3) * 64 + k] * w;
        }
        __syncthreads();
    }
    size_t base = (size_t)(ks * 16 + ty * 4) * ncols + j0 + tx;
    cstore(&P[base], a0);
    cstore(&P[base + (size_t)ncols], a1);
    cstore(&P[base + (size_t)2 * ncols], a2);
    cstore(&P[base + (size_t)3 * ncols], a3);
}

// transposed weight (W_score is [out, K])
__device__ __forceinline__ void gemv_wt(const double* __restrict__ A,
        const float* __restrict__ Wt, double* __restrict__ P, int ncols,
        int j0, int k0, int klen, int ks, double* As, float* Ws) {
    int tid = threadIdx.x, tx = tid & 63, ty = tid >> 6;
    double a0 = 0, a1 = 0, a2 = 0, a3 = 0;
    for (int kc = 0; kc < klen; kc += 64) {
        stage_as(A, DIM, k0, kc, As, tid);
#pragma unroll
        for (int it = 0; it < 16; ++it) {
            int idx = tid + it * BD;
            int j = idx >> 6, k = idx & 63;
            Ws[k * 65 + j] = Wt[(size_t)(j0 + j) * DIM + k0 + kc + k];
        }
        __syncthreads();
#pragma unroll 8
        for (int k = 0; k < 64; ++k) {
            double w = (double)Ws[k * 65 + tx];
            a0 += As[(ty * 4 + 0) * 64 + k] * w;
            a1 += As[(ty * 4 + 1) * 64 + k] * w;
            a2 += As[(ty * 4 + 2) * 64 + k] * w;
            a3 += As[(ty * 4 + 3) * 64 + k] * w;
        }
        __syncthreads();
    }
    size_t base = (size_t)(ks * 16 + ty * 4) * ncols + j0 + tx;
    cstore(&P[base], a0);
    cstore(&P[base + (size_t)ncols], a1);
    cstore(&P[base + (size_t)2 * ncols], a2);
    cstore(&P[base + (size_t)3 * ncols], a3);
}

// ---------- the persistent step-loop kernel ----------
__global__ __launch_bounds__(256, 2) void k_steps(
    const float* __restrict__ Wqkv, const float* __restrict__ bqkv,
    const float* __restrict__ Wap,  const float* __restrict__ bap,
    const float* __restrict__ g1,   const float* __restrict__ b1,
    const float* __restrict__ g2,   const float* __restrict__ b2,
    const float* __restrict__ Wfc,  const float* __restrict__ bfc,
    const float* __restrict__ Wmp,  const float* __restrict__ bmp,
    const float* __restrict__ gf,   const float* __restrict__ bf,
    const float* __restrict__ Wsc,
    double* __restrict__ Kc, double* __restrict__ Vc,
    double* __restrict__ xl, double* __restrict__ h1,
    double* __restrict__ q,  double* __restrict__ sco,
    double* __restrict__ AOp, double* __restrict__ x2,
    double* __restrict__ h2, double* __restrict__ m_,
    double* __restrict__ hf,
    double* __restrict__ P1, double* __restrict__ P2, double* __restrict__ P3,
    double* __restrict__ P4, double* __restrict__ P5,
    float* __restrict__ out, unsigned* __restrict__ bar)
{
    __shared__ __align__(16) char smem[24864];
    double* As  = (double*)smem;
    float*  Ws  = (float*)(smem + 8192);
    double* red = (double*)(smem + 24832);
    int bid = blockIdx.x, tid = threadIdx.x;

    for (int t = 0; t < NSTEPS; ++t) {
        int S = 256 + t, pos = 255 + t;

        // -- 1: QKV GEMV (h1 @ Wqkv) -> P1 partials. 48 col-tiles x splitK8
        if (bid < 384)
            gemv_std(h1, DIM, Wqkv, 3072, P1, 3072,
                     (bid % 48) * 64, (bid / 48) * 128, 128, bid / 48, As, Ws);
        gridbar(bar, bid);

        // -- 2: combine partials -> q, append K[pos], V[pos]. Batched 8/round.
        if (bid < 48) {
            int col = bid * 64 + (tid & 63);
            for (int bb = (tid >> 6); bb < 16; bb += 4) {
                double v[8];
#pragma unroll
                for (int ks = 0; ks < 8; ++ks)
                    v[ks] = cld1(&P1[((size_t)(ks * 16 + bb)) * 3072 + col]);
                cwait();
                double s = (double)bqkv[col];
#pragma unroll
                for (int ks = 0; ks < 8; ++ks) s += v[ks];
                if (col < 1024)      cstore(&q[bb * DIM + col], s);
                else if (col < 2048) cstore(&Kc[((size_t)bb * SMAX + pos) * DIM + (col - 1024)], s);
                else                 cstore(&Vc[((size_t)bb * SMAX + pos) * DIM + (col - 2048)], s);
            }
        }
        gridbar(bar, bid);

        // -- 3: attention scores. 384 blocks: b x 24 chunks x 12 pos
        if (bid < 384) {
            int b = bid / 24, c = bid % 24;
            double* qs = As;
            {
                int e4 = tid * 4;
                v2d r0 = cld2(&q[b * DIM + e4]);
                v2d r1 = cld2(&q[b * DIM + e4 + 2]);
                cwait();
                qs[e4] = r0.x; qs[e4 + 1] = r0.y; qs[e4 + 2] = r1.x; qs[e4 + 3] = r1.y;
            }
            __syncthreads();
            int w = tid >> 6, lane = tid & 63;
#pragma unroll
            for (int r = 0; r < 3; ++r) {
                int p = c * 12 + w * 3 + r;
                if (p < S) {
                    const double* kp = Kc + ((size_t)b * SMAX + p) * DIM;
                    double acc = 0;
                    if (p == pos) {
                        double kv[16];
#pragma unroll
                        for (int ii = 0; ii < 16; ++ii) kv[ii] = cld1(&kp[lane + 64 * ii]);
                        cwait();
#pragma unroll
                        for (int ii = 0; ii < 16; ++ii) acc += qs[lane + 64 * ii] * kv[ii];
                    } else {
#pragma unroll
                        for (int ii = 0; ii < 16; ++ii) acc += qs[lane + 64 * ii] * kp[lane + 64 * ii];
                    }
                    acc = wred_sum(acc);
                    if (lane == 0) cstore(&sco[b * SMAX + p], acc * 0.03125);  // /sqrt(1024)
                }
            }
        }
        gridbar(bar, bid);

        // -- 4: softmax (redundant per block) + partial PV. 512 blocks
        {
            int b = bid >> 5, sub = bid & 31;
            int dch = sub & 3, sch = sub >> 2;
            double* ps = As;
            double lm = -1e300;
            {
                v2d ra, rb;
                if (tid < 128) ra = cld2(&sco[b * SMAX + 2 * tid]);
                if (tid < 16)  rb = cld2(&sco[b * SMAX + 256 + 2 * tid]);
                cwait();
                if (tid < 128) {
                    ps[2 * tid] = ra.x; ps[2 * tid + 1] = ra.y;
                    lm = fmax(ra.x, ra.y);
                }
                if (tid < 16) {
                    int i = 256 + 2 * tid;
                    if (i < S)     { ps[i] = rb.x;     lm = fmax(lm, rb.x); }
                    if (i + 1 < S) { ps[i + 1] = rb.y; lm = fmax(lm, rb.y); }
                }
            }
            double mx = block_max(lm, red);
            double le = 0;
            for (int i = tid; i < S; i += BD) { double e = exp(ps[i] - mx); ps[i] = e; le += e; }
            double den = block_sum(le, red);
            int d = dch * 256 + tid;
            int p0 = sch * 36, p1 = p0 + 36; if (p1 > S) p1 = S;
            bool fresh = (p1 == S);
            int pe = fresh ? p1 - 1 : p1;
            const double* Vb = Vc + (size_t)b * SMAX * DIM + d;
            double a0 = 0, a1 = 0, a2 = 0, a3 = 0;
            int p = p0;
            for (; p + 4 <= pe; p += 4) {
                a0 += ps[p + 0] * Vb[(size_t)(p + 0) * DIM];
                a1 += ps[p + 1] * Vb[(size_t)(p + 1) * DIM];
                a2 += ps[p + 2] * Vb[(size_t)(p + 2) * DIM];
                a3 += ps[p + 3] * Vb[(size_t)(p + 3) * DIM];
            }
            for (; p < pe; ++p) a0 += ps[p] * Vb[(size_t)p * DIM];
            if (fresh) { double fv = cld1(&Vb[(size_t)pos * DIM]); cwait(); a0 += ps[pos] * fv; }
            cstore(&AOp[((size_t)(sch * 16 + b)) * DIM + d], ((a0 + a1) + (a2 + a3)) / den);
        }
        gridbar(bar, bid);

        // -- 5: attn-proj GEMV (sum 8 AOp partials during staging). 16 tiles x splitK8
        if (bid < 128)
            gemv_sum8(AOp, Wap, DIM, P2, DIM,
                      (bid % 16) * 64, (bid / 16) * 128, 128, bid / 16, As, Ws);
        gridbar(bar, bid);

        // -- 6: x2 = xl + aproj + bias; LN2 -> h2. 16 blocks. Batched loads.
        if (bid < 16) {
            int b = bid;
            double* xs = As;
            {
                int e = tid * 4;
                v2d xa = cld2(&xl[b * DIM + e]);
                v2d xb = cld2(&xl[b * DIM + e + 2]);
                v2d pa[4], pb[4];
#pragma unroll
                for (int k4 = 0; k4 < 4; ++k4) {
                    const double* pp = &P2[((size_t)(k4 * 16 + b)) * DIM + e];
                    pa[k4] = cld2(pp); pb[k4] = cld2(pp + 2);
                }
                cwait();
                double s0 = xa.x + (double)bap[e + 0];
                double s1 = xa.y + (double)bap[e + 1];
                double s2 = xb.x + (double)bap[e + 2];
                double s3 = xb.y + (double)bap[e + 3];
#pragma unroll
                for (int k4 = 0; k4 < 4; ++k4) { s0 += pa[k4].x; s1 += pa[k4].y; s2 += pb[k4].x; s3 += pb[k4].y; }
#pragma unroll
                for (int k4 = 0; k4 < 4; ++k4) {
                    const double* pp = &P2[((size_t)((4 + k4) * 16 + b)) * DIM + e];
                    pa[k4] = cld2(pp); pb[k4] = cld2(pp + 2);
                }
                cwait();
#pragma unroll
                for (int k4 = 0; k4 < 4; ++k4) { s0 += pa[k4].x; s1 += pa[k4].y; s2 += pb[k4].x; s3 += pb[k4].y; }
                xs[e + 0] = s0; xs[e + 1] = s1; xs[e + 2] = s2; xs[e + 3] = s3;
                cstore(&x2[b * DIM + e + 0], s0); cstore(&x2[b * DIM + e + 1], s1);
                cstore(&x2[b * DIM + e + 2], s2); cstore(&x2[b * DIM + e + 3], s3);
            }
            __syncthreads();
            double s = 0;
            for (int i = tid; i < DIM; i += BD) s += xs[i];
            s = block_sum(s, red);
            double mean = s * (1.0 / 1024.0);
            double ss = 0;
            for (int i = tid; i < DIM; i += BD) { double dd = xs[i] - mean; ss += dd * dd; }
            ss = block_sum(ss, red);
            double r = 1.0 / sqrt(ss * (1.0 / 1024.0) + 1e-5);
            for (int i = tid; i < DIM; i += BD)
                cstore(&h2[b * DIM + i], (xs[i] - mean) * r * (double)g2[i] + (double)b2[i]);
        }
        gridbar(bar, bid);

        // -- 7: FC GEMV. 64 tiles x splitK8 = 512 blocks
        gemv_std(h2, DIM, Wfc, 4096, P3, 4096,
                 (bid % 64) * 64, (bid / 64) * 128, 128, bid / 64, As, Ws);
        gridbar(bar, bid);

        // -- 8: gelu -> m. 256 blocks. Batched 8 loads.
        if (bid < 256) {
            int b = bid >> 4, i = (bid & 15) * BD + tid;
            double v[8];
#pragma unroll
            for (int ks = 0; ks < 8; ++ks)
                v[ks] = cld1(&P3[((size_t)(ks * 16 + b)) * 4096 + i]);
            cwait();
            double u = (double)bfc[i];
#pragma unroll
            for (int ks = 0; ks < 8; ++ks) u += v[ks];
            double inner = 0.7978845608028654 * (u + 0.044715 * u * u * u);
            cstore(&m_[(size_t)b * 4096 + i], 0.5 * u * (1.0 + tanh(inner)));
        }
        gridbar(bar, bid);

        // -- 9: MPROJ GEMV. 16 tiles x splitK16 (klen 256) = 256 blocks
        if (bid < 256)
            gemv_std(m_, 4096, Wmp, DIM, P4, DIM,
                     (bid % 16) * 64, (bid / 16) * 256, 256, bid / 16, As, Ws);
        gridbar(bar, bid);

        // -- 10: x3 = x2 + mproj + bias; LNf -> hf. 16 blocks. Batched loads.
        if (bid < 16) {
            int b = bid;
            double* xs = As;
            {
                int e = tid * 4;
                v2d xa = cld2(&x2[b * DIM + e]);
                v2d xb = cld2(&x2[b * DIM + e + 2]);
                v2d pa[4], pb[4];
#pragma unroll
                for (int k4 = 0; k4 < 4; ++k4) {
                    const double* pp = &P4[((size_t)(k4 * 16 + b)) * DIM + e];
                    pa[k4] = cld2(pp); pb[k4] = cld2(pp + 2);
                }
                cwait();
                double s0 = xa.x + (double)bmp[e + 0];
                double s1 = xa.y + (double)bmp[e + 1];
                double s2 = xb.x + (double)bmp[e + 2];
                double s3 = xb.y + (double)bmp[e + 3];
#pragma unroll
                for (int k4 = 0; k4 < 4; ++k4) { s0 += pa[k4].x; s1 += pa[k4].y; s2 += pb[k4].x; s3 += pb[k4].y; }
#pragma unroll
                for (int grp = 1; grp < 4; ++grp) {
#pragma unroll
                    for (int k4 = 0; k4 < 4; ++k4) {
                        const double* pp = &P4[((size_t)((grp * 4 + k4) * 16 + b)) * DIM + e];
                        pa[k4] = cld2(pp); pb[k4] = cld2(pp + 2);
                    }
                    cwait();
#pragma unroll
                    for (int k4 = 0; k4 < 4; ++k4) { s0 += pa[k4].x; s1 += pa[k4].y; s2 += pb[k4].x; s3 += pb[k4].y; }
                }
                xs[e + 0] = s0; xs[e + 1] = s1; xs[e + 2] = s2; xs[e + 3] = s3;
            }
            __syncthreads();
            double s = 0;
            for (int i = tid; i < DIM; i += BD) s += xs[i];
            s = block_sum(s, red);
            double mean = s * (1.0 / 1024.0);
            double ss = 0;
            for (int i = tid; i < DIM; i += BD) { double dd = xs[i] - mean; ss += dd * dd; }
            ss = block_sum(ss, red);
            double r = 1.0 / sqrt(ss * (1.0 / 1024.0) + 1e-5);
            for (int i = tid; i < DIM; i += BD)
                cstore(&hf[b * DIM + i], (xs[i] - mean) * r * (double)gf[i] + (double)bf[i]);
        }
        gridbar(bar, bid);

        // -- 11: classification head (W_score^T). 8 tiles x splitK8 = 64 blocks
        if (bid < 64)
            gemv_wt(hf, Wsc, P5, NPROPS,
                    (bid % 8) * 64, (bid / 8) * 128, 128, bid / 8, As, Ws);
        gridbar(bar, bid);

        // -- 12: logits + threshold -> xl, analytic LN1 -> next h1. Batched.
        if (bid < 16) {
            int b = bid;
            double* xs = As;
            double cnt = 0;
            for (int p = tid; p < NPROPS; p += BD) {
                double v[8];
#pragma unroll
                for (int ks = 0; ks < 8; ++ks)
                    v[ks] = cld1(&P5[((size_t)(ks * 16 + b)) * NPROPS + p]);
                cwait();
                double lg = 0;
#pragma unroll
                for (int ks = 0; ks < 8; ++ks) lg += v[ks];
                out[((size_t)b * NSTEPS + t) * NPROPS + p] = (float)lg;
                double bit = (lg > 0.0) ? 1.0 : 0.0;
                xs[p] = bit;
                cstore(&xl[b * DIM + p], 0.0);
                cstore(&xl[b * DIM + NPROPS + p], bit);
                cnt += bit;
            }
            double s = block_sum(cnt, red);
            double mean = s * (1.0 / 1024.0);
            double var = mean - mean * mean;
            double r = 1.0 / sqrt(var + 1e-5);
            for (int i = tid; i < DIM; i += BD) {
                double x = (i < NPROPS) ? 0.0 : xs[i - NPROPS];
                cstore(&h1[b * DIM + i], (x - mean) * r * (double)g1[i] + (double)b1[i]);
            }
        }
        gridbar(bar, bid);
    }
}

extern "C" void kernel_launch(void* const* d_in, const int* in_sizes, int n_in,
                              void* d_out, int out_size, void* d_ws, size_t ws_size,
                              hipStream_t stream) {
    const int*   tok  = (const int*)d_in[0];
    const float* Wqkv = (const float*)d_in[1];
    const float* bqkv = (const float*)d_in[2];
    const float* Wap  = (const float*)d_in[3];
    const float* bap  = (const float*)d_in[4];
    const float* g1   = (const float*)d_in[5];
    const float* b1   = (const float*)d_in[6];
    const float* g2   = (const float*)d_in[7];
    const float* b2   = (const float*)d_in[8];
    const float* Wfc  = (const float*)d_in[9];
    const float* bfc  = (const float*)d_in[10];
    const float* Wmp  = (const float*)d_in[11];
    const float* bmp  = (const float*)d_in[12];
    const float* gf   = (const float*)d_in[13];
    const float* bf   = (const float*)d_in[14];
    const float* Wsc  = (const float*)d_in[15];
    float* out = (float*)d_out;

    char* w = (char*)d_ws;
    size_t off = 0;
    auto alloc = [&](size_t bytes) -> void* {
        void* p = (void*)(w + off);
        off += (bytes + 255) & ~(size_t)255;
        return p;
    };
    double*      Kc   = (double*)alloc((size_t)NB * SMAX * DIM * 8);
    double*      Vc   = (double*)alloc((size_t)NB * SMAX * DIM * 8);
    double*      mu   = (double*)alloc(4096 * 8);
    double*      rs   = (double*)alloc(4096 * 8);
    double*      xl   = (double*)alloc((size_t)NB * DIM * 8);
    double*      h1   = (double*)alloc((size_t)NB * DIM * 8);
    double*      q    = (double*)alloc((size_t)NB * DIM * 8);
    double*      sco  = (double*)alloc((size_t)NB * SMAX * 8);
    double*      AOp  = (double*)alloc((size_t)8 * NB * DIM * 8);
    double*      x2   = (double*)alloc((size_t)NB * DIM * 8);
    double*      h2   = (double*)alloc((size_t)NB * DIM * 8);
    double*      m_   = (double*)alloc((size_t)NB * 4096 * 8);
    double*      hf   = (double*)alloc((size_t)NB * DIM * 8);
    double*      P1   = (double*)alloc((size_t)8 * NB * 3072 * 8);
    double*      P2   = (double*)alloc((size_t)8 * NB * 1024 * 8);
    double*      P3   = (double*)alloc((size_t)8 * NB * 4096 * 8);
    double*      P4   = (double*)alloc((size_t)16 * NB * 1024 * 8);
    double*      P5   = (double*)alloc((size_t)8 * NB * 512 * 8);
    signed char* tokc = (signed char*)alloc((size_t)NTOK);
    unsigned*    bar  = (unsigned*)alloc(16384);
    if (off > ws_size) return;  // fail visibly (output stays poisoned)

    k_tok_convert<<<4096, BD, 0, stream>>>(tok, tokc);
    k_prefix_stats<<<4096, BD, 0, stream>>>(tokc, mu, rs);
    k_init_xl<<<NB, BD, 0, stream>>>(tokc, xl, bar);
    k_prefix<<<dim3(32, 256), BD, 0, stream>>>(tokc, mu, rs, Wqkv, bqkv, g1, b1, Kc, Vc);
    k_ln1<<<NB, BD, 0, stream>>>(xl, g1, b1, h1);

    k_steps<<<NBLK, BD, 0, stream>>>(Wqkv, bqkv, Wap, bap, g1, b1, g2, b2,
                                     Wfc, bfc, Wmp, bmp, gf, bf, Wsc,
                                     Kc, Vc, xl, h1, q, sco, AOp, x2, h2, m_, hf,
                                     P1, P2, P3, P4, P5, out, bar);
}

// Round 6
// 3869.933 us; speedup vs baseline: 2.3488x; 2.1376x over previous
//
#include <hip/hip_runtime.h>
#include <math.h>

#ifndef M_PI
#define M_PI 3.14159265358979323846
#endif

#define BD 256
#define NB 16
#define DIM 1024
#define SMAX 288
#define NSTEPS 32
#define NPROPS 512
#define NTOK (16 * 256 * 1024)

__device__ __forceinline__ double wred_sum(double v) {
#pragma unroll
    for (int o = 32; o > 0; o >>= 1) v += __shfl_down(v, o, 64);
    return v;
}
__device__ __forceinline__ double wred_max(double v) {
#pragma unroll
    for (int o = 32; o > 0; o >>= 1) { double w = __shfl_down(v, o, 64); if (w > v) v = w; }
    return v;
}
__device__ double block_sum(double v, double* sc) {
    v = wred_sum(v);
    int tid = threadIdx.x;
    if ((tid & 63) == 0) sc[tid >> 6] = v;
    __syncthreads();
    double r = sc[0] + sc[1] + sc[2] + sc[3];
    __syncthreads();
    return r;
}
__device__ double block_max(double v, double* sc) {
    v = wred_max(v);
    int tid = threadIdx.x;
    if ((tid & 63) == 0) sc[tid >> 6] = v;
    __syncthreads();
    double r = fmax(fmax(sc[0], sc[1]), fmax(sc[2], sc[3]));
    __syncthreads();
    return r;
}

// ---- canonicalize tokens: handles harness passing int32 OR raw int64 ----
__global__ __launch_bounds__(256) void k_tok_convert(const int* __restrict__ tok32,
                                                     signed char* __restrict__ tokc) {
    __shared__ int flag;
    int tid = threadIdx.x;
    if (tid == 0) {
        int nz = 0;
        for (int i = 1; i < 512; i += 2) nz |= tok32[i];
        flag = nz;
    }
    __syncthreads();
    bool is64 = (flag == 0);
#pragma unroll
    for (int it = 0; it < 4; ++it) {
        size_t idx = (size_t)blockIdx.x * 1024 + it * BD + tid;
        int v = is64 ? tok32[2 * idx] : tok32[idx];
        tokc[idx] = (signed char)v;
    }
}

// ---- prefix: per-token LN stats (tokens are 0/1) ----
__global__ __launch_bounds__(256) void k_prefix_stats(const signed char* __restrict__ tokc,
                                                      double* __restrict__ mu, double* __restrict__ rs) {
    __shared__ double sc[4];
    int T = blockIdx.x, tid = threadIdx.x;
    const signed char* row = tokc + (size_t)T * DIM;
    double s = 0;
    for (int i = tid; i < DIM; i += BD) s += (double)row[i];
    s = block_sum(s, sc);
    double m = s * (1.0 / 1024.0);
    double ss = 0;
    for (int i = tid; i < DIM; i += BD) { double d = (double)row[i] - m; ss += d * d; }
    ss = block_sum(ss, sc);
    if (tid == 0) { mu[T] = m; rs[T] = 1.0 / sqrt(ss * (1.0 / 1024.0) + 1e-5); }
}

// ---- init: xl = last token row; mub/rsb = its LN stats (from prefix_stats) ----
__global__ __launch_bounds__(256) void k_init(const signed char* __restrict__ tokc,
                                              const double* __restrict__ mu, const double* __restrict__ rs,
                                              double* __restrict__ xl,
                                              double* __restrict__ mub, double* __restrict__ rsb) {
    int b = blockIdx.x, tid = threadIdx.x;
    int T = b * 256 + 255;
    if (tid == 0) { mub[b] = mu[T]; rsb[b] = rs[T]; }
    for (int i = tid; i < DIM; i += BD)
        xl[b * DIM + i] = (double)tokc[(size_t)T * DIM + i];
}

// ---- prefix K,V GEMM in fp32: [4096 x 1024] @ Wqkv[:,1024:3072] -> fp32 KV ----
__global__ __launch_bounds__(256) void k_prefix(const signed char* __restrict__ tokc,
        const double* __restrict__ mu, const double* __restrict__ rs,
        const float* __restrict__ Wqkv, const float* __restrict__ bqkv,
        const float* __restrict__ g1, const float* __restrict__ b1,
        float* __restrict__ Kcf, float* __restrict__ Vcf) {
    __shared__ float Hs[64 * 17];   // [k][t], padded
    __shared__ float Ws[64 * 64];   // [k][j]
    int tid = threadIdx.x;
    int tx = tid & 63, ty = tid >> 6;
    int j0 = blockIdx.x * 64;        // kv-col space 0..2047
    int T0 = blockIdx.y * 16;        // token tile
    float acc[4] = {0, 0, 0, 0};
    for (int kc = 0; kc < DIM; kc += 64) {
#pragma unroll
        for (int it = 0; it < 4; ++it) {
            int idx = tid + it * BD;
            int t = idx & 15, k = idx >> 4;
            int T = T0 + t;
            double x = (double)tokc[(size_t)T * DIM + kc + k];
            Hs[k * 17 + t] = (float)((x - mu[T]) * rs[T] * (double)g1[kc + k] + (double)b1[kc + k]);
        }
#pragma unroll
        for (int it = 0; it < 16; ++it) {
            int idx = tid + it * BD;
            int k = idx >> 6, j = idx & 63;
            Ws[k * 64 + j] = Wqkv[(size_t)(kc + k) * 3072 + 1024 + j0 + j];
        }
        __syncthreads();
#pragma unroll 8
        for (int k = 0; k < 64; ++k) {
            float w = Ws[k * 64 + tx];
            acc[0] += Hs[k * 17 + ty * 4 + 0] * w;
            acc[1] += Hs[k * 17 + ty * 4 + 1] * w;
            acc[2] += Hs[k * 17 + ty * 4 + 2] * w;
            acc[3] += Hs[k * 17 + ty * 4 + 3] * w;
        }
        __syncthreads();
    }
    int colg = j0 + tx;
    float bias = bqkv[1024 + colg];
    bool isK = (colg < 1024);
#pragma unroll
    for (int a = 0; a < 4; ++a) {
        int T = T0 + ty * 4 + a;
        int b = T >> 8, pos = T & 255;
        float v = acc[a] + bias;
        if (isK) Kcf[((size_t)b * SMAX + pos) * DIM + colg] = v;
        else     Vcf[((size_t)b * SMAX + pos) * DIM + colg - 1024] = v;
    }
}

// ---- QKV GEMV with analytic-LN staging (xl rows are 0s + bits) ----
// h1[i] = (xl[i]-mub)*rsb*g1[i]+b1[i] computed inline -> no ln1 kernel, no h1 buffer.
__global__ __launch_bounds__(256) void k_qkv(const double* __restrict__ xl,
        const double* __restrict__ mub, const double* __restrict__ rsb,
        const float* __restrict__ g1, const float* __restrict__ b1,
        const float* __restrict__ Wqkv, double* __restrict__ P1) {
    __shared__ double As[16 * 64];
    __shared__ float  Ws[64 * 64];
    int tid = threadIdx.x, tx = tid & 63, ty = tid >> 6;
    int j0 = blockIdx.x * 64;      // 48 tiles over 3072
    int k0 = blockIdx.y * 128;     // splitK8
    double acc[4] = {0, 0, 0, 0};
    for (int kc = 0; kc < 128; kc += 64) {
#pragma unroll
        for (int it = 0; it < 4; ++it) {
            int idx = tid + it * BD;
            int b = idx >> 6, k = idx & 63;
            int kk = k0 + kc + k;
            As[b * 64 + k] = (xl[(size_t)b * DIM + kk] - mub[b]) * rsb[b] * (double)g1[kk] + (double)b1[kk];
        }
#pragma unroll
        for (int it = 0; it < 16; ++it) {
            int idx = tid + it * BD;
            int k = idx >> 6, j = idx & 63;
            Ws[k * 64 + j] = Wqkv[(size_t)(k0 + kc + k) * 3072 + j0 + j];
        }
        __syncthreads();
#pragma unroll 8
        for (int k = 0; k < 64; ++k) {
            double w = (double)Ws[k * 64 + tx];
            acc[0] += As[(ty * 4 + 0) * 64 + k] * w;
            acc[1] += As[(ty * 4 + 1) * 64 + k] * w;
            acc[2] += As[(ty * 4 + 2) * 64 + k] * w;
            acc[3] += As[(ty * 4 + 3) * 64 + k] * w;
        }
        __syncthreads();
    }
#pragma unroll
    for (int a = 0; a < 4; ++a)
        P1[((size_t)(blockIdx.y * 16 + ty * 4 + a)) * 3072 + j0 + tx] = acc[a];
}

// ---- generic batched 16-row GEMV (plain loads; proven baseline form) ----
__global__ __launch_bounds__(256) void mm16(const double* __restrict__ A, int K,
        const float* __restrict__ W, int ldw, double* __restrict__ P, int ncols) {
    __shared__ double As[16 * 64];
    __shared__ float  Ws[64 * 64];
    int tid = threadIdx.x, tx = tid & 63, ty = tid >> 6;
    int j0 = blockIdx.x * 64;
    int klen = K / gridDim.y;
    int k0 = blockIdx.y * klen;
    double acc[4] = {0, 0, 0, 0};
    for (int kc = 0; kc < klen; kc += 64) {
#pragma unroll
        for (int it = 0; it < 4; ++it) {
            int idx = tid + it * BD;
            int b = idx >> 6, k = idx & 63;
            As[b * 64 + k] = A[(size_t)b * K + k0 + kc + k];
        }
#pragma unroll
        for (int it = 0; it < 16; ++it) {
            int idx = tid + it * BD;
            int k = idx >> 6, j = idx & 63;
            Ws[k * 64 + j] = W[(size_t)(k0 + kc + k) * ldw + j0 + j];
        }
        __syncthreads();
#pragma unroll 8
        for (int k = 0; k < 64; ++k) {
            double w = (double)Ws[k * 64 + tx];
            acc[0] += As[(ty * 4 + 0) * 64 + k] * w;
            acc[1] += As[(ty * 4 + 1) * 64 + k] * w;
            acc[2] += As[(ty * 4 + 2) * 64 + k] * w;
            acc[3] += As[(ty * 4 + 3) * 64 + k] * w;
        }
        __syncthreads();
    }
#pragma unroll
    for (int a = 0; a < 4; ++a)
        P[((size_t)(blockIdx.y * 16 + ty * 4 + a)) * ncols + j0 + tx] = acc[a];
}

// ---- transposed-W variant (W_score is [out, K]) ----
__global__ __launch_bounds__(256) void mm16_t(const double* __restrict__ A, int K,
        const float* __restrict__ Wt, double* __restrict__ P, int ncols) {
    __shared__ double As[16 * 64];
    __shared__ float  Ws[64 * 65];
    int tid = threadIdx.x, tx = tid & 63, ty = tid >> 6;
    int j0 = blockIdx.x * 64;
    int klen = K / gridDim.y;
    int k0 = blockIdx.y * klen;
    double acc[4] = {0, 0, 0, 0};
    for (int kc = 0; kc < klen; kc += 64) {
#pragma unroll
        for (int it = 0; it < 4; ++it) {
            int idx = tid + it * BD;
            int b = idx >> 6, k = idx & 63;
            As[b * 64 + k] = A[(size_t)b * K + k0 + kc + k];
        }
#pragma unroll
        for (int it = 0; it < 16; ++it) {
            int idx = tid + it * BD;
            int j = idx >> 6, k = idx & 63;
            Ws[k * 65 + j] = Wt[(size_t)(j0 + j) * K + k0 + kc + k];
        }
        __syncthreads();
#pragma unroll 8
        for (int k = 0; k < 64; ++k) {
            double w = (double)Ws[k * 65 + tx];
            acc[0] += As[(ty * 4 + 0) * 64 + k] * w;
            acc[1] += As[(ty * 4 + 1) * 64 + k] * w;
            acc[2] += As[(ty * 4 + 2) * 64 + k] * w;
            acc[3] += As[(ty * 4 + 3) * 64 + k] * w;
        }
        __syncthreads();
    }
#pragma unroll
    for (int a = 0; a < 4; ++a)
        P[((size_t)(blockIdx.y * 16 + ty * 4 + a)) * ncols + j0 + tx] = acc[a];
}

// ---- combine qkv partials: q fp64 + append fp32 K,V ----
__global__ __launch_bounds__(256) void k_combine_kv(const double* __restrict__ P1, const float* __restrict__ bqkv,
        double* __restrict__ q, float* __restrict__ Kcf, float* __restrict__ Vcf, int pos) {
    int b = blockIdx.x;
    int col = blockIdx.y * BD + threadIdx.x;  // 0..3071
    double s = (double)bqkv[col];
    for (int ks = 0; ks < 8; ++ks) s += P1[((size_t)(ks * 16 + b)) * 3072 + col];
    if (col < 1024)      q[b * DIM + col] = s;
    else if (col < 2048) Kcf[((size_t)b * SMAX + pos) * DIM + col - 1024] = (float)s;
    else                 Vcf[((size_t)b * SMAX + pos) * DIM + col - 2048] = (float)s;
}

// ---- last-row attention scores vs fp32 K (float4 loads) ----
__global__ __launch_bounds__(256) void k_scores(const double* __restrict__ q, const float* __restrict__ Kcf,
                                                double* __restrict__ sco, int S) {
    __shared__ double qs[DIM];
    int b = blockIdx.x, tid = threadIdx.x;
    int lane = tid & 63, w = tid >> 6;
    for (int i = tid; i < DIM; i += BD) qs[i] = q[b * DIM + i];
    __syncthreads();
    int base = blockIdx.y * 32 + w * 8;
    for (int r = 0; r < 8; ++r) {
        int pos = base + r;
        if (pos >= S) break;
        const float4* kp4 = (const float4*)(Kcf + ((size_t)b * SMAX + pos) * DIM);
        double acc = 0;
#pragma unroll
        for (int ii = 0; ii < 4; ++ii) {
            float4 kv = kp4[lane + 64 * ii];
            int e = 4 * (lane + 64 * ii);
            acc += qs[e] * (double)kv.x + qs[e + 1] * (double)kv.y
                 + qs[e + 2] * (double)kv.z + qs[e + 3] * (double)kv.w;
        }
        acc = wred_sum(acc);
        if (lane == 0) sco[b * SMAX + pos] = acc * 0.03125;  // /sqrt(1024)
    }
}

// ---- softmax (redundant/block) + partial PV over fp32 V. grid (16, 32) ----
__global__ __launch_bounds__(256) void k_attnp(const double* __restrict__ sco, const float* __restrict__ Vcf,
                                               double* __restrict__ AOp, int S) {
    __shared__ double ps[SMAX];
    __shared__ double sc[4];
    int b = blockIdx.x, sub = blockIdx.y, tid = threadIdx.x;
    int dch = sub & 3, sch = sub >> 2;
    double lm = -1e300;
    for (int i = tid; i < S; i += BD) { double v = sco[b * SMAX + i]; ps[i] = v; if (v > lm) lm = v; }
    __syncthreads();
    double mx = block_max(lm, sc);
    double le = 0;
    for (int i = tid; i < S; i += BD) { double e = exp(ps[i] - mx); ps[i] = e; le += e; }
    double den = block_sum(le, sc);
    int d = dch * 256 + tid;
    int p0 = sch * 36, p1 = p0 + 36; if (p1 > S) p1 = S;
    const float* Vb = Vcf + (size_t)b * SMAX * DIM + d;
    double a0 = 0, a1 = 0, a2 = 0, a3 = 0;
    int p = p0;
    for (; p + 4 <= p1; p += 4) {
        a0 += ps[p + 0] * (double)Vb[(size_t)(p + 0) * DIM];
        a1 += ps[p + 1] * (double)Vb[(size_t)(p + 1) * DIM];
        a2 += ps[p + 2] * (double)Vb[(size_t)(p + 2) * DIM];
        a3 += ps[p + 3] * (double)Vb[(size_t)(p + 3) * DIM];
    }
    for (; p < p1; ++p) a0 += ps[p] * (double)Vb[(size_t)p * DIM];
    AOp[((size_t)(sch * 16 + b)) * DIM + d] = ((a0 + a1) + (a2 + a3)) / den;
}

// ---- attn-proj GEMV: stage sum of 8 AOp partials, then GEMV Wap -> P2 ----
__global__ __launch_bounds__(256) void k_aproj(const double* __restrict__ AOp,
        const float* __restrict__ Wap, double* __restrict__ P2) {
    __shared__ double As[16 * 64];
    __shared__ float  Ws[64 * 64];
    int tid = threadIdx.x, tx = tid & 63, ty = tid >> 6;
    int j0 = blockIdx.x * 64;      // 16 tiles over 1024
    int k0 = blockIdx.y * 128;     // splitK8
    double acc[4] = {0, 0, 0, 0};
    for (int kc = 0; kc < 128; kc += 64) {
#pragma unroll
        for (int it = 0; it < 4; ++it) {
            int idx = tid + it * BD;
            int b = idx >> 6, k = idx & 63;
            const double* col = AOp + (size_t)b * DIM + k0 + kc + k;
            double s = 0;
#pragma unroll
            for (int sct = 0; sct < 8; ++sct) s += col[(size_t)sct * 16 * DIM];
            As[b * 64 + k] = s;
        }
#pragma unroll
        for (int it = 0; it < 16; ++it) {
            int idx = tid + it * BD;
            int k = idx >> 6, j = idx & 63;
            Ws[k * 64 + j] = Wap[(size_t)(k0 + kc + k) * DIM + j0 + j];
        }
        __syncthreads();
#pragma unroll 8
        for (int k = 0; k < 64; ++k) {
            double w = (double)Ws[k * 64 + tx];
            acc[0] += As[(ty * 4 + 0) * 64 + k] * w;
            acc[1] += As[(ty * 4 + 1) * 64 + k] * w;
            acc[2] += As[(ty * 4 + 2) * 64 + k] * w;
            acc[3] += As[(ty * 4 + 3) * 64 + k] * w;
        }
        __syncthreads();
    }
#pragma unroll
    for (int a = 0; a < 4; ++a)
        P2[((size_t)(blockIdx.y * 16 + ty * 4 + a)) * DIM + j0 + tx] = acc[a];
}

// ---- x2 = xl + aproj + bias; LN2 -> h2 ----
__global__ __launch_bounds__(256) void k_ln2(const double* __restrict__ xl, const double* __restrict__ P2,
        const float* __restrict__ bap, const float* __restrict__ g2, const float* __restrict__ b2,
        double* __restrict__ x2, double* __restrict__ h2) {
    __shared__ double xs[DIM];
    __shared__ double sc[4];
    int b = blockIdx.x, tid = threadIdx.x;
    for (int i = tid; i < DIM; i += BD) {
        double s = xl[b * DIM + i] + (double)bap[i];
        for (int ks = 0; ks < 8; ++ks) s += P2[((size_t)(ks * 16 + b)) * DIM + i];
        xs[i] = s; x2[b * DIM + i] = s;
    }
    __syncthreads();
    double s = 0;
    for (int i = tid; i < DIM; i += BD) s += xs[i];
    s = block_sum(s, sc);
    double m = s * (1.0 / 1024.0);
    double ss = 0;
    for (int i = tid; i < DIM; i += BD) { double d = xs[i] - m; ss += d * d; }
    ss = block_sum(ss, sc);
    double r = 1.0 / sqrt(ss * (1.0 / 1024.0) + 1e-5);
    for (int i = tid; i < DIM; i += BD)
        h2[b * DIM + i] = (xs[i] - m) * r * (double)g2[i] + (double)b2[i];
}

// ---- m = gelu_new(fc + bias) ----
__global__ __launch_bounds__(256) void k_gelu(const double* __restrict__ P3, const float* __restrict__ bfc,
                                              double* __restrict__ m) {
    int b = blockIdx.x;
    int i = blockIdx.y * BD + threadIdx.x;  // 0..4095
    double u = (double)bfc[i];
    for (int ks = 0; ks < 8; ++ks) u += P3[((size_t)(ks * 16 + b)) * 4096 + i];
    double c = sqrt(2.0 / M_PI);
    double inner = c * (u + 0.044715 * u * u * u);
    m[(size_t)b * 4096 + i] = 0.5 * u * (1.0 + tanh(inner));
}

// ---- x3 = x2 + mproj + bias; LNf -> hf (sums 16 partials) ----
__global__ __launch_bounds__(256) void k_lnf(const double* __restrict__ x2, const double* __restrict__ P4,
        const float* __restrict__ bmp, const float* __restrict__ gf, const float* __restrict__ bf,
        double* __restrict__ hf) {
    __shared__ double xs[DIM];
    __shared__ double sc[4];
    int b = blockIdx.x, tid = threadIdx.x;
    for (int i = tid; i < DIM; i += BD) {
        double s = x2[b * DIM + i] + (double)bmp[i];
        for (int ks = 0; ks < 16; ++ks) s += P4[((size_t)(ks * 16 + b)) * DIM + i];
        xs[i] = s;
    }
    __syncthreads();
    double s = 0;
    for (int i = tid; i < DIM; i += BD) s += xs[i];
    s = block_sum(s, sc);
    double m = s * (1.0 / 1024.0);
    double ss = 0;
    for (int i = tid; i < DIM; i += BD) { double d = xs[i] - m; ss += d * d; }
    ss = block_sum(ss, sc);
    double r = 1.0 / sqrt(ss * (1.0 / 1024.0) + 1e-5);
    for (int i = tid; i < DIM; i += BD)
        hf[b * DIM + i] = (xs[i] - m) * r * (double)gf[i] + (double)bf[i];
}

// ---- logits + threshold -> xl; analytic LN1 stats for next step ----
__global__ __launch_bounds__(256) void k_final(const double* __restrict__ P5, float* __restrict__ out,
                                               double* __restrict__ xl,
                                               double* __restrict__ mub, double* __restrict__ rsb, int t) {
    __shared__ double sc[4];
    int b = blockIdx.x, tid = threadIdx.x;
    double cnt = 0;
    for (int p = tid; p < NPROPS; p += BD) {
        double lg = 0;
        for (int ks = 0; ks < 8; ++ks) lg += P5[((size_t)(ks * 16 + b)) * NPROPS + p];
        out[((size_t)b * NSTEPS + t) * NPROPS + p] = (float)lg;
        double bit = (lg > 0.0) ? 1.0 : 0.0;
        xl[b * DIM + p] = 0.0;
        xl[b * DIM + NPROPS + p] = bit;
        cnt += bit;
    }
    double s = block_sum(cnt, sc);
    double mean = s * (1.0 / 1024.0);       // row is [0]*512 + bits
    double var = mean - mean * mean;        // exact in fp64 for integer counts
    double r = 1.0 / sqrt(var + 1e-5);
    if (tid == 0) { mub[b] = mean; rsb[b] = r; }
}

extern "C" void kernel_launch(void* const* d_in, const int* in_sizes, int n_in,
                              void* d_out, int out_size, void* d_ws, size_t ws_size,
                              hipStream_t stream) {
    const int*   tok  = (const int*)d_in[0];
    const float* Wqkv = (const float*)d_in[1];
    const float* bqkv = (const float*)d_in[2];
    const float* Wap  = (const float*)d_in[3];
    const float* bap  = (const float*)d_in[4];
    const float* g1   = (const float*)d_in[5];
    const float* b1   = (const float*)d_in[6];
    const float* g2   = (const float*)d_in[7];
    const float* b2   = (const float*)d_in[8];
    const float* Wfc  = (const float*)d_in[9];
    const float* bfc  = (const float*)d_in[10];
    const float* Wmp  = (const float*)d_in[11];
    const float* bmp  = (const float*)d_in[12];
    const float* gf   = (const float*)d_in[13];
    const float* bf   = (const float*)d_in[14];
    const float* Wsc  = (const float*)d_in[15];
    float* out = (float*)d_out;

    char* w = (char*)d_ws;
    size_t off = 0;
    auto alloc = [&](size_t bytes) -> void* {
        void* p = (void*)(w + off);
        off += (bytes + 255) & ~(size_t)255;
        return p;
    };
    float*       Kcf  = (float*)alloc((size_t)NB * SMAX * DIM * 4);
    float*       Vcf  = (float*)alloc((size_t)NB * SMAX * DIM * 4);
    double*      mu   = (double*)alloc(4096 * 8);
    double*      rs   = (double*)alloc(4096 * 8);
    double*      mub  = (double*)alloc(NB * 8);
    double*      rsb  = (double*)alloc(NB * 8);
    double*      xl   = (double*)alloc((size_t)NB * DIM * 8);
    double*      q    = (double*)alloc((size_t)NB * DIM * 8);
    double*      sco  = (double*)alloc((size_t)NB * SMAX * 8);
    double*      AOp  = (double*)alloc((size_t)8 * NB * DIM * 8);
    double*      x2   = (double*)alloc((size_t)NB * DIM * 8);
    double*      h2   = (double*)alloc((size_t)NB * DIM * 8);
    double*      m_   = (double*)alloc((size_t)NB * 4096 * 8);
    double*      hf   = (double*)alloc((size_t)NB * DIM * 8);
    double*      P1   = (double*)alloc((size_t)8 * NB * 3072 * 8);
    double*      P2   = (double*)alloc((size_t)8 * NB * 1024 * 8);
    double*      P3   = (double*)alloc((size_t)8 * NB * 4096 * 8);
    double*      P4   = (double*)alloc((size_t)16 * NB * 1024 * 8);
    double*      P5   = (double*)alloc((size_t)8 * NB * 512 * 8);
    signed char* tokc = (signed char*)alloc((size_t)NTOK);
    if (off > ws_size) return;  // fail visibly (output stays poisoned)

    k_tok_convert<<<4096, BD, 0, stream>>>(tok, tokc);
    k_prefix_stats<<<4096, BD, 0, stream>>>(tokc, mu, rs);
    k_init<<<NB, BD, 0, stream>>>(tokc, mu, rs, xl, mub, rsb);
    k_prefix<<<dim3(32, 256), BD, 0, stream>>>(tokc, mu, rs, Wqkv, bqkv, g1, b1, Kcf, Vcf);

    for (int t = 0; t < NSTEPS; ++t) {
        int S = 256 + t, pos = 255 + t;
        k_qkv<<<dim3(48, 8), BD, 0, stream>>>(xl, mub, rsb, g1, b1, Wqkv, P1);
        k_combine_kv<<<dim3(NB, 12), BD, 0, stream>>>(P1, bqkv, q, Kcf, Vcf, pos);
        k_scores<<<dim3(NB, 9), BD, 0, stream>>>(q, Kcf, sco, S);
        k_attnp<<<dim3(NB, 32), BD, 0, stream>>>(sco, Vcf, AOp, S);
        k_aproj<<<dim3(16, 8), BD, 0, stream>>>(AOp, Wap, P2);
        k_ln2<<<NB, BD, 0, stream>>>(xl, P2, bap, g2, b2, x2, h2);
        mm16<<<dim3(64, 8), BD, 0, stream>>>(h2, 1024, Wfc, 4096, P3, 4096);
        k_gelu<<<dim3(NB, 16), BD, 0, stream>>>(P3, bfc, m_);
        mm16<<<dim3(16, 16), BD, 0, stream>>>(m_, 4096, Wmp, 1024, P4, 1024);
        k_lnf<<<NB, BD, 0, stream>>>(x2, P4, bmp, gf, bf, hf);
        mm16_t<<<dim3(8, 8), BD, 0, stream>>>(hf, 1024, Wsc, P5, 512);
        k_final<<<NB, BD, 0, stream>>>(P5, out, xl, mub, rsb, t);
    }
}